// Round 1
// baseline (237.156 us; speedup 1.0000x reference)
//
#include <hip/hip_runtime.h>

#define B_  8
#define T_  2048
#define D_  1024
#define H_  16
#define HD_ 64
#define SC_ 16
#define NC_ 16
#define CT_ 128

typedef __attribute__((ext_vector_type(8))) short short8;
typedef __attribute__((ext_vector_type(4))) float f32x4;

__device__ inline unsigned short f2bf(float f) {
  union { float f; unsigned u; } v; v.f = f;
  unsigned r = v.u + 0x7FFFu + ((v.u >> 16) & 1u);
  return (unsigned short)(r >> 16);
}
__device__ inline float bf2f(unsigned short b) {
  union { unsigned u; float f; } v; v.u = ((unsigned)b) << 16; return v.f;
}

// ---------------- fp32 -> bf16 convert (vectorized) ----------------
__global__ void conv_f32_bf16(const float* __restrict__ in,
                              unsigned short* __restrict__ out, int n4) {
  int i = blockIdx.x * 256 + threadIdx.x;
  if (i >= n4) return;
  float4 v = ((const float4*)in)[i];
  ushort4 o;
  o.x = f2bf(v.x); o.y = f2bf(v.y); o.z = f2bf(v.z); o.w = f2bf(v.w);
  ((ushort4*)out)[i] = o;
}

// ---------------- bf16 GEMM: C[M,N] = A[M,K] @ Bt[N,K]^T ----------------
// 128x128 tile, BK=64, 256 threads (4 waves 2x2), mfma_f32_16x16x32_bf16.
// LDS tiles [128 rows][64 k] bf16 with 16B-chunk XOR swizzle (chunk ^= row&7).
template<int OUT_BF16>
__global__ __launch_bounds__(256, 2)
void gemm_bt(const unsigned short* __restrict__ A,
             const unsigned short* __restrict__ Bt,
             void* __restrict__ Cout, int M, int N, int K) {
  __shared__ unsigned short As[128 * 64];
  __shared__ unsigned short Bs[128 * 64];
  const int tid  = threadIdx.x;
  const int lane = tid & 63;
  const int w    = tid >> 6;
  const int wm   = w >> 1, wn = w & 1;
  const int l15  = lane & 15, l4 = lane >> 4;
  const int nbn  = N >> 7;
  const int nwg  = gridDim.x;
  int bid = blockIdx.x;
  // bijective XCD swizzle (grid % 8 == 0 here)
  int b2 = ((nwg & 7) == 0) ? ((bid & 7) * (nwg >> 3) + (bid >> 3)) : bid;
  const int bm = (b2 / nbn) << 7;
  const int bn = (b2 % nbn) << 7;

  f32x4 acc[4][4] = {};

  for (int k0 = 0; k0 < K; k0 += 64) {
    // stage 128x64 bf16 tiles of A and Bt (each = 1024 x 16B chunks)
#pragma unroll
    for (int i = 0; i < 4; ++i) {
      int idx = i * 256 + tid;          // 0..1023
      int row = idx >> 3, c = idx & 7;  // 8 chunks per row
      int csw = c ^ (row & 7);
      int4 va = *(const int4*)(A + (size_t)(bm + row) * K + k0 + c * 8);
      *(int4*)(&As[row * 64 + csw * 8]) = va;
      int4 vb = *(const int4*)(Bt + (size_t)(bn + row) * K + k0 + c * 8);
      *(int4*)(&Bs[row * 64 + csw * 8]) = vb;
    }
    __syncthreads();
#pragma unroll
    for (int ks = 0; ks < 2; ++ks) {
      short8 af[4], bf[4];
#pragma unroll
      for (int i = 0; i < 4; ++i) {
        int ra = (wm << 6) + (i << 4) + l15;
        int kc = (ks << 2) + l4;
        af[i] = *(const short8*)(&As[ra * 64 + ((kc ^ (ra & 7)) << 3)]);
        int rb = (wn << 6) + (i << 4) + l15;
        bf[i] = *(const short8*)(&Bs[rb * 64 + ((kc ^ (rb & 7)) << 3)]);
      }
#pragma unroll
      for (int mi = 0; mi < 4; ++mi)
#pragma unroll
        for (int ni = 0; ni < 4; ++ni)
          acc[mi][ni] = __builtin_amdgcn_mfma_f32_16x16x32_bf16(
              af[mi], bf[ni], acc[mi][ni], 0, 0, 0);
    }
    __syncthreads();
  }

  // epilogue: C/D layout col = lane&15, row = (lane>>4)*4 + reg
  const int rbase = bm + (wm << 6) + (l4 << 2);
  const int cbase = bn + (wn << 6) + l15;
#pragma unroll
  for (int mi = 0; mi < 4; ++mi)
#pragma unroll
    for (int ni = 0; ni < 4; ++ni)
#pragma unroll
      for (int r = 0; r < 4; ++r) {
        size_t row = rbase + (mi << 4) + r;
        int col = cbase + (ni << 4);
        if (OUT_BF16)
          ((unsigned short*)Cout)[row * N + col] = f2bf(acc[mi][ni][r]);
        else
          ((float*)Cout)[row * N + col] = acc[mi][ni][r];
      }
}

// ---------------- scan pass 1: per-chunk local state ----------------
// thread -> (b, c, hh, d); scans CT_ steps from S=0, writes S_end.
__global__ void scan_pass1(const unsigned short* __restrict__ hb,
                           const unsigned char* __restrict__ pad,
                           const float* __restrict__ ldec,
                           float* __restrict__ Send,
                           float* __restrict__ akeep) {
  int gid = blockIdx.x * 256 + threadIdx.x;
  int d  = gid & 63;
  int hh = (gid >> 6) & 15;
  int c  = (gid >> 10) & 15;
  int b  = gid >> 14;
  float dec[SC_], S[SC_];
#pragma unroll
  for (int s = 0; s < SC_; ++s) {
    dec[s] = 1.f / (1.f + __expf(-ldec[hh * SC_ + s]));
    S[s] = 0.f;
  }
  const int t0 = c * CT_;
  const unsigned short* hp = hb + (size_t)(b * T_ + t0) * D_ + hh * HD_ + d;
  const unsigned char* pp = pad + b * T_ + t0;
  float ak = 1.f;
  for (int t = 0; t < CT_; ++t) {
    float ht = bf2f(*hp); hp += D_;
    float k = pp[t] ? 0.f : 1.f;
    ak = fminf(ak, k);
#pragma unroll
    for (int s = 0; s < SC_; ++s) S[s] = (dec[s] * S[s] + ht) * k;
  }
  size_t base = ((size_t)((b * NC_ + c) * H_ + hh) * SC_) * HD_ + d;
#pragma unroll
  for (int s = 0; s < SC_; ++s) Send[base + s * HD_] = S[s];
  if (hh == 0 && d == 0) akeep[b * NC_ + c] = ak;
}

// ---------------- scan pass 1.5: combine chunk carries ----------------
// thread -> (b, hh, s, d); sequential over NC_ chunks.
__global__ void scan_combine(const float* __restrict__ Send,
                             float* __restrict__ Sstart,
                             const float* __restrict__ akeep,
                             const float* __restrict__ ldec) {
  int gid = blockIdx.x * 256 + threadIdx.x;
  int d  = gid & 63;
  int s  = (gid >> 6) & 15;
  int hh = (gid >> 10) & 15;
  int b  = gid >> 14;
  float dec  = 1.f / (1.f + __expf(-ldec[hh * SC_ + s]));
  float dpow = __powf(dec, (float)CT_);
  float carry = 0.f;
  for (int c = 0; c < NC_; ++c) {
    size_t idx = ((size_t)((b * NC_ + c) * H_ + hh) * SC_ + s) * HD_ + d;
    Sstart[idx] = carry;
    float Ac = (akeep[b * NC_ + c] != 0.f) ? dpow : 0.f;
    carry = Ac * carry + Send[idx];
  }
}

// ---------------- scan pass 2: replay + read + gate combine ----------------
// thread -> (b, c, hh, d); emits y (bf16) for the final GEMM.
__global__ void scan_pass2(const unsigned short* __restrict__ hb,
                           const unsigned char* __restrict__ pad,
                           const float* __restrict__ ldec,
                           const float* __restrict__ mix,
                           const float* __restrict__ Sstart,
                           const float* __restrict__ gpre,
                           const float* __restrict__ bgate,
                           const float* __restrict__ x,
                           unsigned short* __restrict__ yb) {
  int gid = blockIdx.x * 256 + threadIdx.x;
  int d  = gid & 63;
  int hh = (gid >> 6) & 15;
  int c  = (gid >> 10) & 15;
  int b  = gid >> 14;
  float dec[SC_], mx[SC_], S[SC_];
  size_t sbase = ((size_t)((b * NC_ + c) * H_ + hh) * SC_) * HD_ + d;
#pragma unroll
  for (int s = 0; s < SC_; ++s) {
    dec[s] = 1.f / (1.f + __expf(-ldec[hh * SC_ + s]));
    mx[s]  = mix[(hh * SC_ + s) * HD_ + d];
    S[s]   = Sstart[sbase + s * HD_];
  }
  const int t0 = c * CT_;
  const int col = hh * HD_ + d;
  const float bg = bgate[col];
  size_t off = (size_t)(b * T_ + t0) * D_ + col;
  const unsigned char* pp = pad + b * T_ + t0;
  for (int t = 0; t < CT_; ++t, off += D_) {
    float ht = bf2f(hb[off]);
    float k = pp[t] ? 0.f : 1.f;
    float rd = 0.f;
#pragma unroll
    for (int s = 0; s < SC_; ++s) {
      S[s] = (dec[s] * S[s] + ht) * k;
      rd += mx[s] * S[s];
    }
    float g  = 1.f / (1.f + __expf(-(gpre[off] + bg)));
    float xv = x[off];
    yb[off] = f2bf(g * rd + (1.f - g) * xv);
  }
}

// ---------------- launch ----------------
extern "C" void kernel_launch(void* const* d_in, const int* in_sizes, int n_in,
                              void* d_out, int out_size, void* d_ws, size_t ws_size,
                              hipStream_t stream) {
  const float* x          = (const float*)d_in[0];
  const unsigned char* pm = (const unsigned char*)d_in[1];
  const float* W_in       = (const float*)d_in[2];
  const float* smix       = (const float*)d_in[3];
  const float* ldec       = (const float*)d_in[4];
  const float* W_gate     = (const float*)d_in[5];
  const float* b_gate     = (const float*)d_in[6];
  const float* W_out      = (const float*)d_in[7];
  float* out = (float*)d_out;
  char* ws = (char*)d_ws;

  const int NX = B_ * T_ * D_;      // 16777216
  const int NW = D_ * D_;           // 1048576

  unsigned short* xb    = (unsigned short*)(ws);                       // 33.5 MB (y aliases after scan)
  unsigned short* wbin  = (unsigned short*)(ws + 33554432);            // 2 MB
  unsigned short* wbgt  = (unsigned short*)(ws + 35651584);            // 2 MB
  unsigned short* wbout = (unsigned short*)(ws + 37748736);            // 2 MB
  unsigned short* hb    = (unsigned short*)(ws + 39845888);            // 33.5 MB (bf16 h)
  float* Send           = (float*)(ws + 73400320);                     // 8 MB
  float* Sstart         = (float*)(ws + 81788928);                     // 8 MB
  float* akeep          = (float*)(ws + 90177536);                     // 512 B
  float* gpre           = out;                                         // d_out as scratch

  conv_f32_bf16<<<NX / 1024, 256, 0, stream>>>(x, xb, NX / 4);
  conv_f32_bf16<<<NW / 1024, 256, 0, stream>>>(W_in,   wbin,  NW / 4);
  conv_f32_bf16<<<NW / 1024, 256, 0, stream>>>(W_gate, wbgt,  NW / 4);
  conv_f32_bf16<<<NW / 1024, 256, 0, stream>>>(W_out,  wbout, NW / 4);

  const int M = B_ * T_;  // 16384
  dim3 gg((M / 128) * (D_ / 128));  // 1024 blocks

  gemm_bt<1><<<gg, 256, 0, stream>>>(xb, wbin, hb,   M, D_, D_);   // h (bf16)
  gemm_bt<0><<<gg, 256, 0, stream>>>(xb, wbgt, gpre, M, D_, D_);   // gate preact (fp32, in d_out)

  dim3 sg(B_ * NC_ * H_ * HD_ / 256);  // 512 blocks
  scan_pass1 <<<sg, 256, 0, stream>>>(hb, pm, ldec, Send, akeep);
  scan_combine<<<sg, 256, 0, stream>>>(Send, Sstart, akeep, ldec);
  scan_pass2 <<<sg, 256, 0, stream>>>(hb, pm, ldec, smix, Sstart, gpre, b_gate, x, xb /* y reuses xb */);

  gemm_bt<0><<<gg, 256, 0, stream>>>(xb, wbout, out, M, D_, D_);   // final output
}

// Round 2
// 215.619 us; speedup vs baseline: 1.0999x; 1.0999x over previous
//
#include <hip/hip_runtime.h>

#define B_  8
#define T_  2048
#define D_  1024
#define H_  16
#define HD_ 64
#define SC_ 16
#define NC_ 32
#define CT_ 64

typedef __attribute__((ext_vector_type(8))) short short8;
typedef __attribute__((ext_vector_type(4))) float f32x4;

__device__ inline unsigned short f2bf(float f) {
  union { float f; unsigned u; } v; v.f = f;
  unsigned r = v.u + 0x7FFFu + ((v.u >> 16) & 1u);
  return (unsigned short)(r >> 16);
}
__device__ inline float bf2f(unsigned short b) {
  union { unsigned u; float f; } v; v.u = ((unsigned)b) << 16; return v.f;
}

__device__ inline void gl_lds16(const unsigned short* g, unsigned short* l) {
  __builtin_amdgcn_global_load_lds(
      (const __attribute__((address_space(1))) unsigned int*)(g),
      (__attribute__((address_space(3))) unsigned int*)(l), 16, 0, 0);
}

// ---------------- fp32 -> bf16 convert (vectorized) ----------------
__global__ void conv_f32_bf16(const float* __restrict__ in,
                              unsigned short* __restrict__ out, int n4) {
  int i = blockIdx.x * 256 + threadIdx.x;
  if (i >= n4) return;
  float4 v = ((const float4*)in)[i];
  ushort4 o;
  o.x = f2bf(v.x); o.y = f2bf(v.y); o.z = f2bf(v.z); o.w = f2bf(v.w);
  ((ushort4*)out)[i] = o;
}

// ---------------- bf16 GEMM: C[M,N] = A[M,K] @ Bt[N,K]^T ----------------
// 128x128 tile, BK=64, 256 threads (4 waves 2x2), mfma_f32_16x16x32_bf16.
// Staging via global_load_lds width=16 with pre-swizzled global source:
// LDS slot s at row r holds global 16B-chunk s^(r&7); lane l (covering row
// q*8+(l>>3), slot l&7) therefore fetches global chunk (l&7)^(l>>3).
// ds_read applies the same XOR -> 2-way banks (free).
template<int OUT_BF16>
__global__ __launch_bounds__(256, 2)
void gemm_bt(const unsigned short* __restrict__ A,
             const unsigned short* __restrict__ Bt,
             void* __restrict__ Cout, int M, int N, int K) {
  __shared__ unsigned short As[128 * 64];
  __shared__ unsigned short Bs[128 * 64];
  const int tid  = threadIdx.x;
  const int lane = tid & 63;
  const int w    = tid >> 6;
  const int wm   = w >> 1, wn = w & 1;
  const int l15  = lane & 15, l4 = lane >> 4;
  const int srow   = lane >> 3;              // row within 8-row chunk
  const int schunk = (lane & 7) ^ srow;      // pre-swizzled global chunk
  const int nbn  = N >> 7;
  const int nwg  = gridDim.x;
  int bid = blockIdx.x;
  int b2 = ((nwg & 7) == 0) ? ((bid & 7) * (nwg >> 3) + (bid >> 3)) : bid;
  const int bm = (b2 / nbn) << 7;
  const int bn = (b2 % nbn) << 7;

  f32x4 acc[4][4] = {};

  for (int k0 = 0; k0 < K; k0 += 64) {
#pragma unroll
    for (int i = 0; i < 4; ++i) {
      int q = (w << 2) + i;                 // 0..15: 8-row chunk
      int r = (q << 3) + srow;              // row 0..127
      gl_lds16(A  + (size_t)(bm + r) * K + k0 + (schunk << 3), As + (q << 9));
      gl_lds16(Bt + (size_t)(bn + r) * K + k0 + (schunk << 3), Bs + (q << 9));
    }
    __syncthreads();
#pragma unroll
    for (int ks = 0; ks < 2; ++ks) {
      short8 af[4], bf[4];
#pragma unroll
      for (int i = 0; i < 4; ++i) {
        int ra = (wm << 6) + (i << 4) + l15;
        int kc = (ks << 2) + l4;
        af[i] = *(const short8*)(&As[ra * 64 + ((kc ^ (ra & 7)) << 3)]);
        int rb = (wn << 6) + (i << 4) + l15;
        bf[i] = *(const short8*)(&Bs[rb * 64 + ((kc ^ (rb & 7)) << 3)]);
      }
#pragma unroll
      for (int mi = 0; mi < 4; ++mi)
#pragma unroll
        for (int ni = 0; ni < 4; ++ni)
          acc[mi][ni] = __builtin_amdgcn_mfma_f32_16x16x32_bf16(
              af[mi], bf[ni], acc[mi][ni], 0, 0, 0);
    }
    __syncthreads();
  }

  // epilogue: C/D layout col = lane&15, row = (lane>>4)*4 + reg
  const int rbase = bm + (wm << 6) + (l4 << 2);
  const int cbase = bn + (wn << 6) + l15;
#pragma unroll
  for (int mi = 0; mi < 4; ++mi)
#pragma unroll
    for (int ni = 0; ni < 4; ++ni)
#pragma unroll
      for (int r = 0; r < 4; ++r) {
        size_t row = rbase + (mi << 4) + r;
        int col = cbase + (ni << 4);
        if (OUT_BF16)
          ((unsigned short*)Cout)[row * N + col] = f2bf(acc[mi][ni][r]);
        else
          ((float*)Cout)[row * N + col] = acc[mi][ni][r];
      }
}

// ---------------- scan pass 1: per-chunk local end-state ----------------
// thread -> (b, c, hh, d); scans CT_ steps from S=0, writes Schunk.
__global__ void scan_pass1(const unsigned short* __restrict__ hb,
                           const unsigned char* __restrict__ pad,
                           const float* __restrict__ ldec,
                           float* __restrict__ Schunk,
                           float* __restrict__ akeep) {
  int gid = blockIdx.x * 256 + threadIdx.x;
  int d  = gid & 63;
  int hh = (gid >> 6) & 15;
  int c  = (gid >> 10) & (NC_ - 1);
  int b  = gid >> 15;
  float dec[SC_], S[SC_];
#pragma unroll
  for (int s = 0; s < SC_; ++s) {
    dec[s] = 1.f / (1.f + __expf(-ldec[hh * SC_ + s]));
    S[s] = 0.f;
  }
  const int t0 = c * CT_;
  const unsigned short* hp = hb + (size_t)(b * T_ + t0) * D_ + hh * HD_ + d;
  const unsigned char* pp = pad + b * T_ + t0;
  float ak = 1.f;
  for (int t = 0; t < CT_; ++t) {
    float ht = bf2f(*hp); hp += D_;
    float k = pp[t] ? 0.f : 1.f;
    ak = fminf(ak, k);
#pragma unroll
    for (int s = 0; s < SC_; ++s) S[s] = (dec[s] * S[s] + ht) * k;
  }
  size_t base = ((size_t)((b * NC_ + c) * H_ + hh) * SC_) * HD_ + d;
#pragma unroll
  for (int s = 0; s < SC_; ++s) Schunk[base + s * HD_] = S[s];
  if (hh == 0 && d == 0) akeep[b * NC_ + c] = ak;
}

// ---------------- scan pass 1.5: in-place carry combine ----------------
// thread -> (b, hh, s, d); Schunk[c] : end-state -> start-state.
__global__ void scan_combine(float* __restrict__ Schunk,
                             const float* __restrict__ akeep,
                             const float* __restrict__ ldec) {
  int gid = blockIdx.x * 256 + threadIdx.x;
  int d  = gid & 63;
  int s  = (gid >> 6) & 15;
  int hh = (gid >> 10) & 15;
  int b  = gid >> 14;
  float dec  = 1.f / (1.f + __expf(-ldec[hh * SC_ + s]));
  float dpow = __powf(dec, (float)CT_);
  float carry = 0.f;
  for (int c = 0; c < NC_; ++c) {
    size_t idx = ((size_t)((b * NC_ + c) * H_ + hh) * SC_ + s) * HD_ + d;
    float e = Schunk[idx];
    Schunk[idx] = carry;
    float Ac = (akeep[b * NC_ + c] != 0.f) ? dpow : 0.f;
    carry = Ac * carry + e;
  }
}

// ---------------- scan pass 2: replay + read + gate combine ----------------
// thread -> (b, c, hh, d); reads bf16 gate-preact + bf16 x, emits y (bf16).
__global__ void scan_pass2(const unsigned short* __restrict__ hb,
                           const unsigned char* __restrict__ pad,
                           const float* __restrict__ ldec,
                           const float* __restrict__ mix,
                           const float* __restrict__ Sstart,
                           const unsigned short* __restrict__ gpre,
                           const float* __restrict__ bgate,
                           unsigned short* __restrict__ xy) {
  int gid = blockIdx.x * 256 + threadIdx.x;
  int d  = gid & 63;
  int hh = (gid >> 6) & 15;
  int c  = (gid >> 10) & (NC_ - 1);
  int b  = gid >> 15;
  float dec[SC_], mx[SC_], S[SC_];
  size_t sbase = ((size_t)((b * NC_ + c) * H_ + hh) * SC_) * HD_ + d;
#pragma unroll
  for (int s = 0; s < SC_; ++s) {
    dec[s] = 1.f / (1.f + __expf(-ldec[hh * SC_ + s]));
    mx[s]  = mix[(hh * SC_ + s) * HD_ + d];
    S[s]   = Sstart[sbase + s * HD_];
  }
  const int t0 = c * CT_;
  const int col = hh * HD_ + d;
  const float bg = bgate[col];
  size_t off = (size_t)(b * T_ + t0) * D_ + col;
  const unsigned char* pp = pad + b * T_ + t0;
  for (int t = 0; t < CT_; ++t, off += D_) {
    float ht = bf2f(hb[off]);
    float k = pp[t] ? 0.f : 1.f;
    float rd = 0.f;
#pragma unroll
    for (int s = 0; s < SC_; ++s) {
      S[s] = (dec[s] * S[s] + ht) * k;
      rd += mx[s] * S[s];
    }
    float g  = 1.f / (1.f + __expf(-(bf2f(gpre[off]) + bg)));
    float xv = bf2f(xy[off]);
    xy[off] = f2bf(g * rd + (1.f - g) * xv);
  }
}

// ---------------- launch ----------------
extern "C" void kernel_launch(void* const* d_in, const int* in_sizes, int n_in,
                              void* d_out, int out_size, void* d_ws, size_t ws_size,
                              hipStream_t stream) {
  const float* x          = (const float*)d_in[0];
  const unsigned char* pm = (const unsigned char*)d_in[1];
  const float* W_in       = (const float*)d_in[2];
  const float* smix       = (const float*)d_in[3];
  const float* ldec       = (const float*)d_in[4];
  const float* W_gate     = (const float*)d_in[5];
  const float* b_gate     = (const float*)d_in[6];
  const float* W_out      = (const float*)d_in[7];
  float* out = (float*)d_out;
  char* ws = (char*)d_ws;

  const int NX = B_ * T_ * D_;      // 16777216
  const int NW = D_ * D_;           // 1048576

  unsigned short* xb    = (unsigned short*)(ws);              // 33.5 MB (y aliases)
  unsigned short* wbin  = (unsigned short*)(ws + 33554432);   // 2 MB
  unsigned short* wbgt  = (unsigned short*)(ws + 35651584);   // 2 MB
  unsigned short* wbout = (unsigned short*)(ws + 37748736);   // 2 MB
  unsigned short* hb    = (unsigned short*)(ws + 39845888);   // 33.5 MB
  float* Schunk         = (float*)(ws + 73400320);            // 16 MB (NC=32)
  float* akeep          = (float*)(ws + 90177536);            // 1 KB
  unsigned short* gpre  = (unsigned short*)d_out;             // bf16 scratch in d_out

  conv_f32_bf16<<<NX / 1024, 256, 0, stream>>>(x, xb, NX / 4);
  conv_f32_bf16<<<NW / 1024, 256, 0, stream>>>(W_in,   wbin,  NW / 4);
  conv_f32_bf16<<<NW / 1024, 256, 0, stream>>>(W_gate, wbgt,  NW / 4);
  conv_f32_bf16<<<NW / 1024, 256, 0, stream>>>(W_out,  wbout, NW / 4);

  const int M = B_ * T_;  // 16384
  dim3 gg((M / 128) * (D_ / 128));  // 1024 blocks

  gemm_bt<1><<<gg, 256, 0, stream>>>(xb, wbin, hb,   M, D_, D_);   // h (bf16)
  gemm_bt<1><<<gg, 256, 0, stream>>>(xb, wbgt, gpre, M, D_, D_);   // gate preact (bf16, in d_out)

  dim3 sg1(B_ * NC_ * H_ * HD_ / 256);  // 1024 blocks
  dim3 sgc(B_ * H_ * SC_ * HD_ / 256);  // 512 blocks
  scan_pass1 <<<sg1, 256, 0, stream>>>(hb, pm, ldec, Schunk, akeep);
  scan_combine<<<sgc, 256, 0, stream>>>(Schunk, akeep, ldec);
  scan_pass2 <<<sg1, 256, 0, stream>>>(hb, pm, ldec, smix, Schunk, gpre, b_gate, xb);

  gemm_bt<0><<<gg, 256, 0, stream>>>(xb, wbout, out, M, D_, D_);   // final output
}